// Round 8
// baseline (124.484 us; speedup 1.0000x reference)
//
#include <hip/hip_runtime.h>
#include <math.h>

#define HOP     200
#define NB      32
#define TLEN    480000
#define NSEGG   2404                   // segments g in [-2, 2401] (incl. edge pads)
#define QPB     16                     // output segments per synth block
#define NQB     (TLEN / HOP / QPB)     // 150
#define NSEGP   22                     // staged segments per synth block
#define SEGPB   25                     // segments per K1 block
#define NGB     ((NSEGG + SEGPB - 1) / SEGPB)   // 97

#define DLT  0.00785398163397448f      // 2*pi/800
// cos/sin of k*DLT, k=1..3 (within-float4 angle stepping)
#define C1K  0.99996915760f
#define S1K  0.00785390090f
#define C2K  0.99987663248f
#define S2K  0.01570731731f
#define C3K  0.99972243010f
#define S3K  0.02355976470f
// rotation by 40*DLT = pi/10 (between a thread's successive float4s)
#define C40  0.95105651629515f
#define S40  0.30901699437495f

typedef float floatx4 __attribute__((ext_vector_type(4)));   // native vec for nontemporal store

// Analytic collapse (validated R1-R6):
//   out[p] = 0.75*x[t] + A'(q,par) - R'(q,par)*cos(p*DLT - psi)  [+ edge w^2 corr]
// from per-segment basis partials P1,Pc,Ps (x read exactly once in K1), via
//   w[n] = 0.5 + 0.5*(cos(pi*f/2)*cos(t*DLT) + sin(pi*f/2)*sin(t*DLT))

// K1: register-accumulated per-segment partials, one LDS fold, no shuffles.
__global__ __launch_bounds__(256) void seg_partials(const float* __restrict__ x,
                                                    float* __restrict__ P) {
    __shared__ float part[SEGPB][10][6];    // 6 KB
    const int b  = blockIdx.y;
    const int s0 = blockIdx.x * SEGPB;
    const float* xb = x + (size_t)b * TLEN;
    const int t = threadIdx.x;

    if (t < SEGPB * 10) {
        const int s = t / 10;
        const int k = t - 10 * s;
        const int sg = s0 + s;
        if (sg < NSEGG) {
            const int g  = sg - 2;             // [-2, 2401]
            const int gm = (g + 4) & 3;
            float c0, sn0;
            __sincosf((float)(gm * 200 + 4 * k) * DLT, &sn0, &c0);
            float p1e = 0.f, p1o = 0.f, pce = 0.f, pco = 0.f, pse = 0.f, pso = 0.f;
            const bool inb = (g >= 0) && (g <= 2399);
            float4 ve;
            if (!inb) {
                const float xe = (g < 0) ? xb[0] : xb[TLEN - 1];
                ve = make_float4(xe, xe, xe, xe);
            }
#pragma unroll
            for (int i = 0; i < 5; ++i) {
                float4 v;
                if (inb) v = ((const float4*)(xb + 200 * g))[k + 10 * i];
                else     v = ve;
                const float c1 = c0 * C1K - sn0 * S1K, s1 = sn0 * C1K + c0 * S1K;
                const float c2 = c0 * C2K - sn0 * S2K, s2 = sn0 * C2K + c0 * S2K;
                const float c3 = c0 * C3K - sn0 * S3K, s3 = sn0 * C3K + c0 * S3K;
                p1e += v.x + v.z;             p1o += v.y + v.w;
                pce += c0 * v.x + c2 * v.z;   pco += c1 * v.y + c3 * v.w;
                pse += sn0 * v.x + s2 * v.z;  pso += s1 * v.y + s3 * v.w;
                const float cn = c0 * C40 - sn0 * S40;   // advance 40 samples
                sn0 = sn0 * C40 + c0 * S40;  c0 = cn;
            }
            part[s][k][0] = p1e;  part[s][k][1] = p1o;
            part[s][k][2] = pce;  part[s][k][3] = pco;
            part[s][k][4] = pse;  part[s][k][5] = pso;
        }
    }
    __syncthreads();

    if (t < SEGPB * 6) {
        const int s = t / 6;
        const int c = t - 6 * s;
        const int sg = s0 + s;
        if (sg < NSEGG) {
            float a = 0.f;
#pragma unroll
            for (int k = 0; k < 10; ++k) a += part[s][k][c];
            P[((size_t)b * NSEGG + sg) * 6 + c] = a;   // coalesced 150-float run
        }
    }
}

// K2: stage partials, build per-(segment,parity) trig constants, stream synth.
__global__ __launch_bounds__(256) void synth(const float* __restrict__ x,
                                             const float* __restrict__ P,
                                             float* __restrict__ out) {
    __shared__ float  pg[NSEGP][6];
    __shared__ float4 segc[2][QPB];

    const int qb = blockIdx.x;
    const int b  = blockIdx.y;
    const int q0 = qb * QPB;
    const float* xb = x + (size_t)b * TLEN;

    if (threadIdx.x < NSEGP * 6) {
        const int sl = threadIdx.x / 6;
        const int c  = threadIdx.x - 6 * sl;
        int g = q0 - 3 + sl;                   // [-3, 2402]
        g = min(max(g, -2), 2401);             // clamped slots are masked later
        pg[sl][c] = P[((size_t)b * NSEGG + g + 2) * 6 + c];
    }
    __syncthreads();

    if (threadIdx.x < 2 * QPB) {
        const int par = threadIdx.x & 1;
        const int ql  = threadIdx.x >> 1;
        const int q   = q0 + ql;
        float A = 0.f, C = 0.f, D = 0.f;
#pragma unroll
        for (int df = -1; df <= 2; ++df) {
            const int f = q + df;
            if (f < 0 || f > 2400) continue;   // boundary frame mask
            const int ls0 = f - q0 + 1;        // local index of g=f-2
            float sp1 = 0.f, spc = 0.f, sps = 0.f;
#pragma unroll
            for (int kk = 0; kk < 4; ++kk) {
                const float* rec = pg[ls0 + kk];
                sp1 += rec[par];  spc += rec[2 + par];  sps += rec[4 + par];
            }
            const int fm = f & 3;
            const float tr = (fm == 0) ? spc : (fm == 1) ? sps : (fm == 2) ? -spc : -sps;
            const float S = 0.5f * sp1 + 0.5f * tr;
            A += S;
            if (fm == 0) C += S; else if (fm == 2) C -= S;
            else if (fm == 1) D += S; else D -= S;
        }
        segc[par][ql] = make_float4(A * (1.0f / 1600.0f),
                                    sqrtf(C * C + D * D) * (1.0f / 1600.0f),
                                    atan2f(D, C), 0.f);
    }
    __syncthreads();

    const bool headblk = (qb == 0);
    const bool tailblk = (qb == NQB - 1);
    const float4* xg4 = (const float4*)(xb + HOP * q0);
    floatx4* og4 = (floatx4*)(out + (size_t)b * TLEN + HOP * q0);
    const int pmb = (q0 & 3) * 200 + 400;
    for (int j = threadIdx.x; j < 50 * QPB; j += 256) {
        const float4 xv = xg4[j];              // L3-hot (K1 just streamed x)
        const int sl = j / 50;
        const float4 ce = segc[0][sl];
        const float4 co = segc[1][sl];
        const int pm = (pmb + 4 * j) % 800;
        const float xa[4] = {xv.x, xv.y, xv.z, xv.w};
        float r[4];
#pragma unroll
        for (int c = 0; c < 4; ++c) {
            const float4 cc = (c & 1) ? co : ce;
            r[c] = 0.75f * xa[c] + cc.x - cc.y * __cosf((float)(pm + c) * DLT - cc.z);
        }
        if (headblk && sl == 0) {              // missing frame's w^2 term (analytic)
#pragma unroll
            for (int c = 0; c < 4; ++c) {
                const float wm = 0.5f + 0.5f * __sinf((float)(pm + c) * DLT);
                r[c] -= 0.5f * wm * wm * xa[c];
            }
        }
        if (tailblk && sl == QPB - 1) {
#pragma unroll
            for (int c = 0; c < 4; ++c) {
                const float wm = 0.5f - 0.5f * __sinf((float)(pm + c) * DLT);
                r[c] -= 0.5f * wm * wm * xa[c];
            }
        }
        floatx4 rv = {r[0], r[1], r[2], r[3]};
        __builtin_nontemporal_store(rv, &og4[j]);
    }
}

extern "C" void kernel_launch(void* const* d_in, const int* in_sizes, int n_in,
                              void* d_out, int out_size, void* d_ws, size_t ws_size,
                              hipStream_t stream) {
    const float* x = (const float*)d_in[0];
    float* out = (float*)d_out;
    float* P   = (float*)d_ws;     // NB*NSEGG*6 floats = 1,846,272 B

    seg_partials<<<dim3(NGB, NB), dim3(256), 0, stream>>>(x, P);
    synth<<<dim3(NQB, NB), dim3(256), 0, stream>>>(x, P, out);
}

// Round 9
// 122.454 us; speedup vs baseline: 1.0166x; 1.0166x over previous
//
#include <hip/hip_runtime.h>
#include <math.h>

#define HOP     200
#define NB      32
#define TLEN    480000
#define SEG     60                     // output segments per block
#define NTILE   (TLEN / HOP / SEG)     // 40
#define NSEGP   (SEG + 6)              // 66 partial segments: [q0-3, q0+62]

#define DLT  0.00785398163397448f      // 2*pi/800
// cos/sin of k*DLT, k=1..3 (within-float4 angle stepping)
#define C1K  0.99996915760f
#define S1K  0.00785390090f
#define C2K  0.99987663248f
#define S2K  0.01570731731f
#define C3K  0.99972243010f
#define S3K  0.02355976470f
// rotation by 40*DLT = pi/10 (between a thread's successive float4s)
#define C40  0.95105651629515f
#define S40  0.30901699437495f

typedef float floatx4 __attribute__((ext_vector_type(4)));

// Analytic collapse (validated R1-R8):
//   out[p] = 0.75*x[t] + A'(q,par) - R'(q,par)*cos(p*DLT - psi)  [+ edge w^2 corr]
// from per-segment basis partials P1,Pc,Ps via
//   w[n] = 0.5 + 0.5*(cos(pi*f/2)*cos(t*DLT) + sin(pi*f/2)*sin(t*DLT)).
// Single kernel, SEG=60 tile: Phase A reads x 1.1x (halo 6/60), Phase D
// re-read is L2-resident. 19.3 KB LDS -> 8 blocks/CU; 1280 blocks total.
__global__ __launch_bounds__(256) void stft_tile(const float* __restrict__ x,
                                                 float* __restrict__ out) {
    __shared__ float  part[NSEGP][10][6];   // 15.8 KB
    __shared__ float  pg[NSEGP][6];         // 1.6 KB
    __shared__ float4 segc[2][SEG];         // 1.9 KB

    const int qb = blockIdx.x;              // [0, NTILE)
    const int b  = blockIdx.y;
    const int q0 = qb * SEG;
    const float* xb = x + (size_t)b * TLEN;

    // ---- Phase A: register-accumulated basis partials (no shuffles) ----
    for (int u = threadIdx.x; u < NSEGP * 10; u += 256) {
        const int s = u / 10;
        const int k = u - 10 * s;
        const int g = q0 - 3 + s;           // [-3, 2402]
        const int gm = (g + 4) & 3;         // t mod 800 phase
        float c0, sn0;
        __sincosf((float)(gm * 200 + 4 * k) * DLT, &sn0, &c0);
        float p1e = 0.f, p1o = 0.f, pce = 0.f, pco = 0.f, pse = 0.f, pso = 0.f;
        const bool inb = (g >= 0) && (g <= 2399);
        float4 ve;
        if (!inb) {                         // edge-pad segment: constant x
            const float xe = (g < 0) ? xb[0] : xb[TLEN - 1];
            ve = make_float4(xe, xe, xe, xe);
        }
#pragma unroll
        for (int i = 0; i < 5; ++i) {
            float4 v;
            if (inb) v = ((const float4*)(xb + 200 * g))[k + 10 * i];
            else     v = ve;
            const float c1 = c0 * C1K - sn0 * S1K, s1 = sn0 * C1K + c0 * S1K;
            const float c2 = c0 * C2K - sn0 * S2K, s2 = sn0 * C2K + c0 * S2K;
            const float c3 = c0 * C3K - sn0 * S3K, s3 = sn0 * C3K + c0 * S3K;
            p1e += v.x + v.z;             p1o += v.y + v.w;
            pce += c0 * v.x + c2 * v.z;   pco += c1 * v.y + c3 * v.w;
            pse += sn0 * v.x + s2 * v.z;  pso += s1 * v.y + s3 * v.w;
            const float cn = c0 * C40 - sn0 * S40;   // advance 40 samples
            sn0 = sn0 * C40 + c0 * S40;  c0 = cn;
        }
        part[s][k][0] = p1e;  part[s][k][1] = p1o;
        part[s][k][2] = pce;  part[s][k][3] = pco;
        part[s][k][4] = pse;  part[s][k][5] = pso;
    }
    __syncthreads();

    // ---- Phase B: fold 10 sub-partials per segment ----
    for (int u = threadIdx.x; u < NSEGP * 6; u += 256) {
        const int s = u / 6;
        const int c = u - 6 * s;
        float a = 0.f;
#pragma unroll
        for (int k = 0; k < 10; ++k) a += part[s][k][c];
        pg[s][c] = a;
    }
    __syncthreads();

    // ---- Phase C: per-(segment,parity) trig constants, masked frames ----
    if (threadIdx.x < 2 * SEG) {
        const int par = threadIdx.x & 1;
        const int ql  = threadIdx.x >> 1;
        const int q   = q0 + ql;
        float A = 0.f, C = 0.f, D = 0.f;
#pragma unroll
        for (int df = -1; df <= 2; ++df) {
            const int f = q + df;
            if (f < 0 || f > 2400) continue;     // boundary frame mask
            const int ls0 = f - q0 + 1;          // local index of g=f-2
            float sp1 = 0.f, spc = 0.f, sps = 0.f;
#pragma unroll
            for (int kk = 0; kk < 4; ++kk) {
                const float* rec = pg[ls0 + kk];
                sp1 += rec[par];  spc += rec[2 + par];  sps += rec[4 + par];
            }
            const int fm = f & 3;
            const float tr = (fm == 0) ? spc : (fm == 1) ? sps : (fm == 2) ? -spc : -sps;
            const float S = 0.5f * sp1 + 0.5f * tr;
            A += S;
            if (fm == 0) C += S; else if (fm == 2) C -= S;
            else if (fm == 1) D += S; else D -= S;
        }
        segc[par][ql] = make_float4(A * (1.0f / 1600.0f),
                                    sqrtf(C * C + D * D) * (1.0f / 1600.0f),
                                    atan2f(D, C), 0.f);
    }
    __syncthreads();

    // ---- Phase D: stream synth (x re-read L2-resident from Phase A) ----
    const bool headblk = (qb == 0);
    const bool tailblk = (qb == NTILE - 1);
    const float4* xg4 = (const float4*)(xb + HOP * q0);
    floatx4* og4 = (floatx4*)(out + (size_t)b * TLEN + HOP * q0);
    const int pmb = (q0 & 3) * 200 + 400;
    for (int j = threadIdx.x; j < 50 * SEG; j += 256) {
        const float4 xv = xg4[j];
        const int sl = j / 50;
        const float4 ce = segc[0][sl];
        const float4 co = segc[1][sl];
        const int pm = (pmb + 4 * j) % 800;
        const float xa[4] = {xv.x, xv.y, xv.z, xv.w};
        float r[4];
#pragma unroll
        for (int c = 0; c < 4; ++c) {
            const float4 cc = (c & 1) ? co : ce;
            r[c] = 0.75f * xa[c] + cc.x - cc.y * __cosf((float)(pm + c) * DLT - cc.z);
        }
        if (headblk && sl == 0) {         // missing frame's w^2 term (analytic)
#pragma unroll
            for (int c = 0; c < 4; ++c) {
                const float wm = 0.5f + 0.5f * __sinf((float)(pm + c) * DLT);
                r[c] -= 0.5f * wm * wm * xa[c];
            }
        }
        if (tailblk && sl == SEG - 1) {
#pragma unroll
            for (int c = 0; c < 4; ++c) {
                const float wm = 0.5f - 0.5f * __sinf((float)(pm + c) * DLT);
                r[c] -= 0.5f * wm * wm * xa[c];
            }
        }
        floatx4 rv = {r[0], r[1], r[2], r[3]};
        __builtin_nontemporal_store(rv, &og4[j]);
    }
}

extern "C" void kernel_launch(void* const* d_in, const int* in_sizes, int n_in,
                              void* d_out, int out_size, void* d_ws, size_t ws_size,
                              hipStream_t stream) {
    const float* x = (const float*)d_in[0];
    float* out = (float*)d_out;
    stft_tile<<<dim3(NTILE, NB), dim3(256), 0, stream>>>(x, out);
}